// Round 5
// baseline (234.255 us; speedup 1.0000x reference)
//
#include <hip/hip_runtime.h>
#include <hip/hip_bf16.h>
#include <stdint.h>

// ---------------------------------------------------------------------------
// BondPoolingLayer: out[e] = MLP(cat(h[src],h[dst])) + MLP(cat(h[dst],h[src]))
// MLP: 256 ->(W1,b1,relu) 128 ->(W2,b2,relu) 128 ->(W3,b3) 2
//
// P[n,0:128] = h[n] @ W1_top ; P[n,128:256] = h[n] @ W1_bot + b1   (bf16)
//   fwd layer1 preact = P[s,0:128] + P[d,128:256]
//   rev layer1 preact = P[d,0:128] + P[s,128:256]
//
// R10 = R9 node_proj (locked: 61us, ideal traffic, coalesced LDS-bounce
//       epilogue) + edge_mlp register diet for gather-latency occupancy.
//  - Session accounting: total - node_proj == ~166us constant across R5-R9
//    => edge_mlp ~= 155us = 70% of runtime. Its MFMA work is ~6us; its
//    220MB of random 512B P-gathers are L3-resident => latency-bound.
//  - R5 edge live-set: g[4][4](64) held across MFMA + acc(64) + consts(24)
//    ~= 170 regs => ~8-12 waves/CU. Fix: addrelu in the gather phase so g
//    retires before acc goes live (peak ~110); epilogue consts from LDS.
//  - Structure stays per-tile + (512,2): persistent loops and reg caps are
//    both proven toxic (R6/R7/R8). Math identical to R7/R8's edge (passed).
// ---------------------------------------------------------------------------

typedef __attribute__((ext_vector_type(8))) short bf16x8;
typedef __attribute__((ext_vector_type(4))) float f32x4;

__device__ __forceinline__ float bf2f(unsigned u16) {
    union { unsigned u; float f; } v; v.u = u16 << 16;
    return v.f;
}
__device__ __forceinline__ unsigned short f2bf(float f) {
    union { float f; unsigned u; } v; v.f = f;
    unsigned u = v.u;
    unsigned r = u + 0x7FFFu + ((u >> 16) & 1u);   // RNE
    return (unsigned short)(r >> 16);
}

// LDS swizzle: tiles are [rows][128 bf16], chunk = 8 bf16 (16B), 16 chunks/row.
__device__ __forceinline__ int swz(int f, int c) {
    return f * 128 + ((c ^ (f & 7)) << 3);
}

// 8 consecutive fp32 -> bf16x8 fragment (packed RNE cvt)
__device__ __forceinline__ bf16x8 cvt8(const float* p) {
    float4 x = *(const float4*)p;
    float4 y = *(const float4*)(p + 4);
    union { bf16x8 v; __hip_bfloat162 h[4]; } R;
    R.h[0] = __float22bfloat162_rn(float2{x.x, x.y});
    R.h[1] = __float22bfloat162_rn(float2{x.z, x.w});
    R.h[2] = __float22bfloat162_rn(float2{y.x, y.y});
    R.h[3] = __float22bfloat162_rn(float2{y.z, y.w});
    return R.v;
}

// elementwise relu(a+b) over 8 bf16 pairs (fp32 math), repacked to bf16x8
__device__ __forceinline__ bf16x8 addrelu8(uint4 a, uint4 b) {
    union { uint4 v; unsigned u[4]; } A, B;
    A.v = a; B.v = b;
    union { bf16x8 v; __hip_bfloat162 h[4]; } R;
#pragma unroll
    for (int i = 0; i < 4; ++i) {
        float a0 = bf2f(A.u[i] & 0xFFFFu), a1 = bf2f(A.u[i] >> 16);
        float b0 = bf2f(B.u[i] & 0xFFFFu), b1 = bf2f(B.u[i] >> 16);
        R.h[i] = __float22bfloat162_rn(float2{fmaxf(a0 + b0, 0.f),
                                              fmaxf(a1 + b1, 0.f)});
    }
    return R.v;
}

#define MFMA(a, b, c) __builtin_amdgcn_mfma_f32_16x16x32_bf16((a), (b), (c), 0, 0, 0)

// ---------------------------------------------------------------------------
// Kernel 0: weight prep (bf16 transposes, plain row-major).
// ---------------------------------------------------------------------------
__global__ void prep_weights(const float* __restrict__ W1,
                             const float* __restrict__ W2,
                             unsigned short* __restrict__ W1t,
                             unsigned short* __restrict__ W2t) {
    int idx = blockIdx.x * 256 + threadIdx.x;
    if (idx < 256 * 128) {
        int j = idx >> 7, k = idx & 127;
        float v = (j < 128) ? W1[k * 128 + j] : W1[(k + 128) * 128 + (j - 128)];
        W1t[idx] = f2bf(v);
    } else {
        int i2 = idx - 256 * 128;
        if (i2 < 128 * 128) {
            int n = i2 >> 7, k = i2 & 127;
            W2t[i2] = f2bf(W2[k * 128 + n]);
        }
    }
}

// ---------------------------------------------------------------------------
// Kernel A: node projection (byte-identical to R9). Per-tile blocks; wave =
// 16 nodes x 256 features; coalesced LDS-bounce epilogue.
// ---------------------------------------------------------------------------
__global__ __launch_bounds__(512, 2) void node_proj(
    const float* __restrict__ h, const unsigned short* __restrict__ W1t,
    const float* __restrict__ b1, unsigned short* __restrict__ P, int nodes) {
    __shared__ unsigned short W1s[256 * 128];   // reused as output staging

    int t = threadIdx.x;
    int lane = t & 63;
    int wv = t >> 6;
    int ml = lane & 15, quad = lane >> 4;

    // stage W1s: thread t -> row t>>1, 8 chunks (swizzled)
    {
        int r = t >> 1, half = t & 1;
        const uint4* srcp = (const uint4*)(W1t + (size_t)r * 128 + half * 64);
#pragma unroll
        for (int i = 0; i < 8; ++i)
            *(uint4*)(W1s + swz(r, half * 8 + i)) = srcp[i];
    }

    // prefetch + convert h for this wave's 16 nodes (B-operand: n = ml)
    int node = blockIdx.x * 128 + wv * 16 + ml;
    int nodeL = (node < nodes) ? node : (nodes - 1);
    const float* hrow = h + (size_t)nodeL * 128;
    bf16x8 bfrag[4];
#pragma unroll
    for (int kk = 0; kk < 4; ++kk)
        bfrag[kk] = cvt8(hrow + kk * 32 + quad * 8);

    __syncthreads();   // W1s ready

    f32x4 acc[16] = {};
#pragma unroll
    for (int kk = 0; kk < 4; ++kk) {
#pragma unroll
        for (int ct = 0; ct < 16; ++ct) {
            bf16x8 afrag = *(const bf16x8*)(W1s + swz(ct * 16 + ml, kk * 4 + quad));
            acc[ct] = MFMA(afrag, bfrag[kk], acc[ct]);
        }
    }

    __syncthreads();   // all waves done READING W1s; safe to overwrite

    // write acc -> LDS staging. Row = wv*16+ml (512B), 16B chunks XOR-swizzled
    // by row so the linear readout below is bank-spread.
    {
        unsigned short* orow = W1s + (wv * 16 + ml) * 256;
#pragma unroll
        for (int ct = 0; ct < 16; ++ct) {
            int fbase = ct * 16 + quad * 4;
            float v0 = acc[ct][0], v1 = acc[ct][1];
            float v2 = acc[ct][2], v3 = acc[ct][3];
            if (fbase >= 128) {
                float4 bv = *(const float4*)(b1 + (fbase - 128));
                v0 += bv.x; v1 += bv.y; v2 += bv.z; v3 += bv.w;
            }
            union { uint2 u; __hip_bfloat162 h2[2]; } o;
            o.h2[0] = __float22bfloat162_rn(float2{v0, v1});
            o.h2[1] = __float22bfloat162_rn(float2{v2, v3});
            int c = ct * 2 + (quad >> 1);          // 16B chunk index in row
            *(uint2*)(orow + ((c ^ ml) << 3) + ((quad & 1) << 2)) = o.u;
        }
    }
    __syncthreads();   // staging ready

    // coalesced readout + store: per thread 8 x dwordx4; per wave-instr 1KB
    // linear. Block's P region (128 rows x 512B) is contiguous.
    {
        size_t pbase = (size_t)blockIdx.x * (128 * 256);
        int nbase = blockIdx.x * 128;
#pragma unroll
        for (int j = 0; j < 8; ++j) {
            int off = wv * 8192 + j * 1024 + lane * 16;   // byte offset in tile
            int row = off >> 9;
            int c = (off & 511) >> 4;
            uint4 v = *(const uint4*)(W1s + row * 256 + ((c ^ (row & 15)) << 3));
            if (nbase + row < nodes)
                *(uint4*)(P + pbase + (off >> 1)) = v;
        }
    }
}

// ---------------------------------------------------------------------------
// Kernel B: per-edge MLP. Per-tile blocks, 512 thr = 8 waves = 128 edges.
// R10: addrelu in the gather phase (g retires before acc is live; MFMA-loop
// live-set ~110 regs vs R5's ~170) + epilogue consts from LDS. More waves
// per CU => more random P-gathers in flight (the latency-bound phase).
// ---------------------------------------------------------------------------
__global__ __launch_bounds__(512, 2) void edge_mlp(
    const unsigned short* __restrict__ P, const int* __restrict__ src,
    const int* __restrict__ dst, const unsigned short* __restrict__ W2t,
    const float* __restrict__ b2, const float* __restrict__ W3,
    const float* __restrict__ b3, float* __restrict__ out, int E) {
    __shared__ unsigned short W2s[128 * 128];
    __shared__ float2 cW3[128];
    __shared__ float  cb2[128];

    int t = threadIdx.x;
    int lane = t & 63;
    int wv = t >> 6;
    int ml = lane & 15, quad = lane >> 4;

    // stage W2s: thread t -> row t>>2, 4 chunks (swizzled)
    {
        int f = t >> 2, q4 = t & 3;
        const uint4* s = (const uint4*)(W2t + (size_t)f * 128 + q4 * 32);
#pragma unroll
        for (int i = 0; i < 4; ++i)
            *(uint4*)(W2s + swz(f, q4 * 4 + i)) = s[i];
    }
    if (t < 128) {
        cW3[t] = float2{W3[t * 2 + 0], W3[t * 2 + 1]};
        cb2[t] = b2[t];
    }

    // gather + convert BEFORE the barrier: g chunks retire into afw/arv
    // (32 regs) so the MFMA loop never holds the 64-reg gather block.
    int e = blockIdx.x * 128 + wv * 16 + ml;
    int ec = (e < E) ? e : (E - 1);
    int si = src[ec], di = dst[ec];
    const unsigned short* Ps = P + (size_t)si * 256;
    const unsigned short* Pd = P + (size_t)di * 256;

    bf16x8 afw[4], arv[4];
#pragma unroll
    for (int kk = 0; kk < 4; ++kk) {
        int ko = kk * 32 + quad * 8;
        uint4 slo = *(const uint4*)(Ps + ko);
        uint4 shi = *(const uint4*)(Ps + 128 + ko);
        uint4 dlo = *(const uint4*)(Pd + ko);
        uint4 dhi = *(const uint4*)(Pd + 128 + ko);
        afw[kk] = addrelu8(slo, dhi);   // fwd: relu(P[s,k]+P[d,128+k])
        arv[kk] = addrelu8(dlo, shi);   // rev: relu(P[d,k]+P[s,128+k])
    }

    __syncthreads();   // W2s ready

    f32x4 acc[2][8] = {};
#pragma unroll
    for (int kk = 0; kk < 4; ++kk) {
#pragma unroll
        for (int ct = 0; ct < 8; ++ct) {
            bf16x8 bfrag = *(const bf16x8*)(W2s + swz(ct * 16 + ml, kk * 4 + quad));
            acc[0][ct] = MFMA(afw[kk], bfrag, acc[0][ct]);
            acc[1][ct] = MFMA(arv[kk], bfrag, acc[1][ct]);
        }
    }

    // epilogue: +b2, relu, dot W3 columns (consts from LDS), fwd+rev folded
    // straight into p0/p1 (R8-proven ordering), butterfly over 16 lanes.
    float p0[4] = {0.f, 0.f, 0.f, 0.f};
    float p1[4] = {0.f, 0.f, 0.f, 0.f};
#pragma unroll
    for (int ct = 0; ct < 8; ++ct) {
        int c = ct * 16 + ml;
        float2 w3 = cW3[c];
        float bc = cb2[c];
#pragma unroll
        for (int rt = 0; rt < 2; ++rt) {
#pragma unroll
            for (int reg = 0; reg < 4; ++reg) {
                float h2 = fmaxf(acc[rt][ct][reg] + bc, 0.f);
                p0[reg] += h2 * w3.x;
                p1[reg] += h2 * w3.y;
            }
        }
    }
#pragma unroll
    for (int m = 1; m < 16; m <<= 1) {
#pragma unroll
        for (int reg = 0; reg < 4; ++reg) {
            p0[reg] += __shfl_xor(p0[reg], m);
            p1[reg] += __shfl_xor(p1[reg], m);
        }
    }

    // lane ml==0 writes component 0, ml==1 writes component 1
    if (ml < 2) {
        float bb = 2.f * b3[ml];
#pragma unroll
        for (int reg = 0; reg < 4; ++reg) {
            int ee = blockIdx.x * 128 + wv * 16 + quad * 4 + reg;
            if (ee < E) {
                float v = (ml == 0) ? p0[reg] : p1[reg];
                out[(size_t)ee * 2 + ml] = v + bb;
            }
        }
    }
}

// ---------------------------------------------------------------------------
extern "C" void kernel_launch(void* const* d_in, const int* in_sizes, int n_in,
                              void* d_out, int out_size, void* d_ws, size_t ws_size,
                              hipStream_t stream) {
    (void)n_in; (void)out_size; (void)ws_size;
    const float* h  = (const float*)d_in[0];
    const int*   sr = (const int*)d_in[1];
    const int*   ds = (const int*)d_in[2];
    const float* W1 = (const float*)d_in[3];
    const float* b1 = (const float*)d_in[4];
    const float* W2 = (const float*)d_in[5];
    const float* b2 = (const float*)d_in[6];
    const float* W3 = (const float*)d_in[7];
    const float* b3 = (const float*)d_in[8];
    float* out = (float*)d_out;

    int nodes = in_sizes[0] / 128;
    int E = in_sizes[1];

    unsigned short* W1t = (unsigned short*)d_ws;          // 256*128
    unsigned short* W2t = W1t + 256 * 128;                // 128*128
    unsigned short* P   = W2t + 128 * 128;                // nodes*256

    prep_weights<<<(256 * 128 + 128 * 128 + 255) / 256, 256, 0, stream>>>(W1, W2, W1t, W2t);

    int ntiles = (nodes + 127) / 128;
    node_proj<<<ntiles, 512, 0, stream>>>(h, W1t, b1, P, nodes);

    int etiles = (E + 127) / 128;
    edge_mlp<<<etiles, 512, 0, stream>>>(P, sr, ds, W2t, b2, W3, b3, out, E);
}